// Round 1
// baseline (2278.836 us; speedup 1.0000x reference)
//
#include <hip/hip_runtime.h>

#define TOKENS 4096
#define DMODEL 768
#define NHEAD 12
#define HDIM 64
#define KSEL 16
#define MDB 32768
#define DFF 3072
#define CHUNK 512
#define NCHUNK 8
#define KCAND 32

typedef __attribute__((ext_vector_type(8))) short short8;
typedef __attribute__((ext_vector_type(4))) float floatx4;

__device__ __forceinline__ unsigned short f2b(float f){
  unsigned int x = __float_as_uint(f);
  unsigned int r = (x + 0x7FFFu + ((x >> 16) & 1u)) >> 16;
  return (unsigned short)r;
}

__device__ __forceinline__ float gelu_new(float x){
  float x3 = x*x*x;
  float t = tanhf(0.7978845608028654f*(x + 0.044715f*x3));
  return 0.5f*x*(1.0f+t);
}

// ---------------- transpose-cast fp32 [R,C](ld) -> bf16 [C,R] ----------------
__global__ __launch_bounds__(256) void tcast_kernel(
    const float* __restrict__ src, unsigned short* __restrict__ dst,
    int R, int C, int ld)
{
  __shared__ float t[32][33];
  int r0 = blockIdx.y*32, c0 = blockIdx.x*32;
  int tx = threadIdx.x & 31, ty = threadIdx.x >> 5;
  #pragma unroll
  for (int i=0;i<4;i++){ int r = ty + i*8; t[r][tx] = src[(size_t)(r0+r)*ld + c0 + tx]; }
  __syncthreads();
  #pragma unroll
  for (int i=0;i<4;i++){ int c = ty + i*8; dst[(size_t)(c0+c)*R + r0 + tx] = f2b(t[tx][c]); }
}

// ---------------- straight cast fp32 -> bf16 ----------------
__global__ __launch_bounds__(256) void cast_bf16_kernel(
    const float* __restrict__ src, unsigned short* __restrict__ dst, int n4)
{
  int i = blockIdx.x*256 + threadIdx.x;
  if (i < n4){
    float4 f = reinterpret_cast<const float4*>(src)[i];
    ushort4 u; u.x = f2b(f.x); u.y = f2b(f.y); u.z = f2b(f.z); u.w = f2b(f.w);
    reinterpret_cast<ushort4*>(dst)[i] = u;
  }
}

// ---------------- layernorm (768), outputs fp32 and/or bf16 ----------------
__global__ __launch_bounds__(256) void ln_kernel(
    const float* __restrict__ x, const float* __restrict__ g, const float* __restrict__ b,
    float* __restrict__ of, unsigned short* __restrict__ ob)
{
  const int token = blockIdx.x, tid = threadIdx.x;
  const float* xr = x + (size_t)token*DMODEL;
  float v[3];
  #pragma unroll
  for (int i=0;i<3;i++) v[i] = xr[tid + i*256];
  float s = v[0]+v[1]+v[2];
  __shared__ float red[8];
  #pragma unroll
  for (int off=32; off; off>>=1) s += __shfl_down(s, off);
  int lane = tid & 63, wv = tid >> 6;
  if (lane == 0) red[wv] = s;
  __syncthreads();
  if (tid == 0) red[4] = (red[0]+red[1]+red[2]+red[3]) * (1.0f/768.0f);
  __syncthreads();
  float mean = red[4];
  float d0 = v[0]-mean, d1 = v[1]-mean, d2 = v[2]-mean;
  float q = d0*d0 + d1*d1 + d2*d2;
  __syncthreads();
  #pragma unroll
  for (int off=32; off; off>>=1) q += __shfl_down(q, off);
  if (lane == 0) red[wv] = q;
  __syncthreads();
  if (tid == 0) red[5] = rsqrtf((red[0]+red[1]+red[2]+red[3]) * (1.0f/768.0f) + 1e-5f);
  __syncthreads();
  float rstd = red[5];
  #pragma unroll
  for (int i=0;i<3;i++){
    int d = tid + i*256;
    float o = (v[i]-mean)*rstd*g[d] + b[d];
    if (of) of[(size_t)token*DMODEL + d] = o;
    if (ob) ob[(size_t)token*DMODEL + d] = f2b(o);
  }
}

// ---------------- fp32 SGEMM for q (precision-critical) ----------------
// C[m,n] = sum_k A[m,k]*W[k,n] + bias[n], n < 768, W ld = 2304
__global__ __launch_bounds__(256) void sgemm_q(
    const float* __restrict__ A, const float* __restrict__ W,
    const float* __restrict__ bias, float* __restrict__ qf,
    unsigned short* __restrict__ qb)
{
  __shared__ float As[16][65];
  __shared__ float Bs[16][65];
  const int tid = threadIdx.x;
  const int tx = tid & 15, ty = tid >> 4;
  const int m0 = blockIdx.y * 64, n0 = blockIdx.x * 64;
  float acc[4][4] = {};
  for (int k0 = 0; k0 < DMODEL; k0 += 16){
    #pragma unroll
    for (int i=0;i<4;i++){
      int lin = tid + i*256;
      int r = lin >> 4, c = lin & 15;
      As[c][r] = A[(size_t)(m0+r)*DMODEL + k0 + c];
    }
    #pragma unroll
    for (int i=0;i<4;i++){
      int lin = tid + i*256;
      int r = lin >> 6, c = lin & 63;
      Bs[r][c] = W[(size_t)(k0+r)*(3*DMODEL) + n0 + c];
    }
    __syncthreads();
    #pragma unroll
    for (int k=0;k<16;k++){
      float av[4], bv[4];
      #pragma unroll
      for (int i=0;i<4;i++) av[i] = As[k][ty + 16*i];
      #pragma unroll
      for (int j=0;j<4;j++) bv[j] = Bs[k][tx + 16*j];
      #pragma unroll
      for (int i=0;i<4;i++)
        #pragma unroll
        for (int j=0;j<4;j++)
          acc[i][j] += av[i]*bv[j];
    }
    __syncthreads();
  }
  #pragma unroll
  for (int i=0;i<4;i++){
    int m = m0 + ty + 16*i;
    #pragma unroll
    for (int j=0;j<4;j++){
      int n = n0 + tx + 16*j;
      float v2 = acc[i][j] + bias[n];
      qf[(size_t)m*DMODEL + n] = v2;
      qb[(size_t)m*DMODEL + n] = f2b(v2);
    }
  }
}

// ---------------- bf16 MFMA GEMM: C[m,n] = A[m,k] * Bt[n,k]^T ----------------
// 128x128 tile, BK=32, 4 waves, each wave 32 rows x 128 cols
template<bool GELU>
__global__ __launch_bounds__(256) void gemm_bt(
    const unsigned short* __restrict__ A,
    const unsigned short* __restrict__ Bt,
    const float* __restrict__ bias,
    const float* __restrict__ resid,
    float* __restrict__ Cf,
    unsigned short* __restrict__ Cb,
    int N, int K)
{
  __shared__ __align__(16) unsigned short As[128][40];
  __shared__ __align__(16) unsigned short Bs[128][40];
  const int tid = threadIdx.x;
  const int wave = tid >> 6;
  const int lane = tid & 63;
  const int lr = lane & 15;
  const int quad = lane >> 4;
  const int m0 = blockIdx.y * 128;
  const int n0 = blockIdx.x * 128;

  floatx4 acc[2][8];
  #pragma unroll
  for (int t=0;t<2;t++)
    #pragma unroll
    for (int n=0;n<8;n++)
      acc[t][n] = (floatx4)0.0f;

  for (int k0 = 0; k0 < K; k0 += 32){
    #pragma unroll
    for (int i=0;i<2;i++){
      int lin = tid + i*256;
      int row = lin >> 2;
      int kq = (lin & 3) << 3;
      *reinterpret_cast<uint4*>(&As[row][kq]) =
        *reinterpret_cast<const uint4*>(&A[(size_t)(m0+row)*K + k0 + kq]);
      *reinterpret_cast<uint4*>(&Bs[row][kq]) =
        *reinterpret_cast<const uint4*>(&Bt[(size_t)(n0+row)*K + k0 + kq]);
    }
    __syncthreads();
    short8 af[2], bq[8];
    #pragma unroll
    for (int t=0;t<2;t++)
      af[t] = *reinterpret_cast<const short8*>(&As[wave*32 + t*16 + lr][quad<<3]);
    #pragma unroll
    for (int n=0;n<8;n++)
      bq[n] = *reinterpret_cast<const short8*>(&Bs[n*16 + lr][quad<<3]);
    #pragma unroll
    for (int t=0;t<2;t++)
      #pragma unroll
      for (int n=0;n<8;n++)
        acc[t][n] = __builtin_amdgcn_mfma_f32_16x16x32_bf16(af[t], bq[n], acc[t][n], 0, 0, 0);
    __syncthreads();
  }

  #pragma unroll
  for (int t=0;t<2;t++){
    #pragma unroll
    for (int n=0;n<8;n++){
      int ng = n0 + n*16 + lr;
      float bi = bias ? bias[ng] : 0.0f;
      #pragma unroll
      for (int r=0;r<4;r++){
        int mg = m0 + wave*32 + t*16 + quad*4 + r;
        float v = acc[t][n][r] + bi;
        if (resid) v += resid[(size_t)mg*N + ng];
        if (GELU) v = gelu_new(v);
        if (Cf) Cf[(size_t)mg*N + ng] = v;
        if (Cb) Cb[(size_t)mg*N + ng] = f2b(v);
      }
    }
  }
}

// ---------------- top-32 candidates per token from bf16 scores ----------------
__global__ __launch_bounds__(256) void topk_kernel(
    const float* __restrict__ scores, int* __restrict__ cand, int token_base)
{
  const int tl = blockIdx.x, tid = threadIdx.x;
  const float* row = scores + (size_t)tl * MDB;
  float bv[16]; int bi[16];
  #pragma unroll
  for (int j=0;j<16;j++){ bv[j] = -3.4e38f; bi[j] = 0; }
  float vmin = -3.4e38f; int minpos = 0;
  for (int it=0; it<MDB/256; ++it){
    int e = tid + (it<<8);
    float sv_ = row[e];
    if (sv_ > vmin){
      #pragma unroll
      for (int j=0;j<16;j++) if (j == minpos){ bv[j] = sv_; bi[j] = e; }
      vmin = bv[0]; minpos = 0;
      #pragma unroll
      for (int j=1;j<16;j++) if (bv[j] < vmin){ vmin = bv[j]; minpos = j; }
    }
  }
  __shared__ float sv[256];
  __shared__ int sl[256];
  int* co = cand + (size_t)(token_base + tl) * KCAND;
  for (int r=0;r<KCAND;r++){
    float lm = bv[0]; int lp = 0;
    #pragma unroll
    for (int j=1;j<16;j++) if (bv[j] > lm){ lm = bv[j]; lp = j; }
    sv[tid] = lm; sl[tid] = tid;
    __syncthreads();
    for (int s=128; s>0; s>>=1){
      if (tid < s && sv[tid+s] > sv[tid]){ sv[tid] = sv[tid+s]; sl[tid] = sl[tid+s]; }
      __syncthreads();
    }
    if (tid == sl[0]){ co[r] = bi[lp]; bv[lp] = -3.4e38f; }
    __syncthreads();
  }
}

// ---------------- exact fp32 rescore of 32 candidates -> top-16 ----------------
__global__ __launch_bounds__(256) void rescore_kernel(
    const float* __restrict__ qf, const float* __restrict__ dbk,
    const int* __restrict__ cand, int* __restrict__ idxo)
{
  const int token = blockIdx.x, tid = threadIdx.x;
  __shared__ float qs[768];
  __shared__ int cs[32];
  __shared__ float sval[32];
  #pragma unroll
  for (int i=0;i<3;i++) qs[tid + i*256] = qf[(size_t)token*DMODEL + tid + i*256];
  if (tid < 32) cs[tid] = cand[(size_t)token*KCAND + tid];
  __syncthreads();
  const int c = tid >> 3, sub = tid & 7;
  const float* kr = dbk + (size_t)cs[c]*DMODEL + sub*96;
  const float* qp = qs + sub*96;
  float s = 0.f;
  #pragma unroll
  for (int j=0;j<24;j++){
    float4 a = reinterpret_cast<const float4*>(qp)[j];
    float4 b4 = reinterpret_cast<const float4*>(kr)[j];
    s += a.x*b4.x + a.y*b4.y + a.z*b4.z + a.w*b4.w;
  }
  s += __shfl_xor(s, 1); s += __shfl_xor(s, 2); s += __shfl_xor(s, 4);
  if (sub == 0) sval[c] = s;
  __syncthreads();
  if (tid < 64){
    float v = (tid < 32) ? sval[tid] : -3.4e38f;
    int ci = (tid < 32) ? cs[tid] : 0;
    for (int r=0;r<KSEL;r++){
      float mv = v; int ml = tid;
      #pragma unroll
      for (int off=32; off; off>>=1){
        float ov = __shfl_xor(mv, off);
        int ol = __shfl_xor(ml, off);
        if (ov > mv || (ov == mv && ol < ml)){ mv = ov; ml = ol; }
      }
      int widx = __shfl(ci, ml);
      if (tid == 0) idxo[(size_t)token*KSEL + r] = widx;
      if (tid == ml) v = -3.4e38f;
    }
  }
}

// ---------------- per-token softmax attention over 16 memories ----------------
__global__ __launch_bounds__(256) void attn_kernel(
    const float* __restrict__ qf, const float* __restrict__ dbk, const float* __restrict__ dbv,
    const int* __restrict__ idx, unsigned short* __restrict__ ao)
{
  const int token = blockIdx.x, tid = threadIdx.x;
  __shared__ float qs[768];
  __shared__ int ixs[16];
  __shared__ float awgt[12][16];
  #pragma unroll
  for (int i=0;i<3;i++) qs[tid + i*256] = qf[(size_t)token*DMODEL + tid + i*256];
  if (tid < 16) ixs[tid] = idx[(size_t)token*KSEL + tid];
  __syncthreads();
  if (tid < 192){
    int m = tid / 12, h = tid - m*12;
    const float4* kr = reinterpret_cast<const float4*>(dbk + (size_t)ixs[m]*DMODEL + h*HDIM);
    const float4* qr = reinterpret_cast<const float4*>(qs + h*HDIM);
    float s = 0.f;
    #pragma unroll
    for (int j=0;j<16;j++){
      float4 a = qr[j], b4 = kr[j];
      s += a.x*b4.x + a.y*b4.y + a.z*b4.z + a.w*b4.w;
    }
    awgt[h][m] = s * 0.125f;
  }
  __syncthreads();
  if (tid < 12){
    float mx = awgt[tid][0];
    #pragma unroll
    for (int m=1;m<16;m++) mx = fmaxf(mx, awgt[tid][m]);
    float ssum = 0.f;
    float e[16];
    #pragma unroll
    for (int m=0;m<16;m++){ e[m] = expf(awgt[tid][m]-mx); ssum += e[m]; }
    float inv = 1.0f/ssum;
    #pragma unroll
    for (int m=0;m<16;m++) awgt[tid][m] = e[m]*inv;
  }
  __syncthreads();
  #pragma unroll
  for (int i=0;i<3;i++){
    int d = tid + i*256;
    int h = d >> 6;
    float s = 0.f;
    #pragma unroll
    for (int m=0;m<16;m++) s += awgt[h][m] * dbv[(size_t)ixs[m]*DMODEL + d];
    ao[(size_t)token*DMODEL + d] = f2b(s);
  }
}

extern "C" void kernel_launch(void* const* d_in, const int* in_sizes, int n_in,
                              void* d_out, int out_size, void* d_ws, size_t ws_size,
                              hipStream_t stream) {
  (void)in_sizes; (void)n_in; (void)out_size; (void)ws_size;
  const float* x    = (const float*)d_in[0];
  const float* dbk  = (const float*)d_in[1];
  const float* dbv  = (const float*)d_in[2];
  const float* ln1g = (const float*)d_in[3];
  const float* ln1b = (const float*)d_in[4];
  const float* attw = (const float*)d_in[5];
  const float* attb = (const float*)d_in[6];
  const float* cpw  = (const float*)d_in[7];
  const float* cpb  = (const float*)d_in[8];
  const float* ln2g = (const float*)d_in[9];
  const float* ln2b = (const float*)d_in[10];
  const float* fcw  = (const float*)d_in[11];
  const float* fcb  = (const float*)d_in[12];
  const float* pjw  = (const float*)d_in[13];
  const float* pjb  = (const float*)d_in[14];
  float* out = (float*)d_out;

  char* p = (char*)d_ws;
  auto alloc = [&](size_t bytes) -> void* {
    void* r = (void*)p; p += (bytes + 255) & ~(size_t)255; return r;
  };
  float* h_f32            = (float*)alloc((size_t)TOKENS*DMODEL*4);
  float* q_f32            = (float*)alloc((size_t)TOKENS*DMODEL*4);
  unsigned short* q_b16   = (unsigned short*)alloc((size_t)TOKENS*DMODEL*2);
  unsigned short* dbk16   = (unsigned short*)alloc((size_t)MDB*DMODEL*2);
  unsigned short* wq_t    = (unsigned short*)alloc((size_t)DMODEL*DMODEL*2);
  unsigned short* cp_t    = (unsigned short*)alloc((size_t)DMODEL*DMODEL*2);
  unsigned short* fc_t    = (unsigned short*)alloc((size_t)DMODEL*DFF*2);
  unsigned short* pj_t    = (unsigned short*)alloc((size_t)DMODEL*DFF*2);
  float* scores           = (float*)alloc((size_t)CHUNK*MDB*4);
  int* cand               = (int*)alloc((size_t)TOKENS*KCAND*4);
  int* idxf               = (int*)alloc((size_t)TOKENS*KSEL*4);
  unsigned short* attn16  = (unsigned short*)alloc((size_t)TOKENS*DMODEL*2);
  float* resid2           = (float*)alloc((size_t)TOKENS*DMODEL*4);
  unsigned short* h2_16   = (unsigned short*)alloc((size_t)TOKENS*DMODEL*2);
  unsigned short* ff1     = (unsigned short*)alloc((size_t)TOKENS*DFF*2);

  // weight casts / transposes to [N,K] bf16
  tcast_kernel<<<dim3(24,24),256,0,stream>>>(attw, wq_t, DMODEL, DMODEL, 3*DMODEL);
  tcast_kernel<<<dim3(24,24),256,0,stream>>>(cpw,  cp_t, DMODEL, DMODEL, DMODEL);
  tcast_kernel<<<dim3(96,24),256,0,stream>>>(fcw,  fc_t, DMODEL, DFF,    DFF);
  tcast_kernel<<<dim3(24,96),256,0,stream>>>(pjw,  pj_t, DFF,    DMODEL, DMODEL);
  cast_bf16_kernel<<<(MDB*DMODEL/4+255)/256,256,0,stream>>>(dbk, dbk16, MDB*DMODEL/4);

  // ln1 -> h (fp32 for precision-critical q GEMM)
  ln_kernel<<<TOKENS,256,0,stream>>>(x, ln1g, ln1b, h_f32, nullptr);
  // q = h @ c_attn_w[:, :768] + b  (fp32)
  sgemm_q<<<dim3(12, TOKENS/64),256,0,stream>>>(h_f32, attw, attb, q_f32, q_b16);

  // approximate scores (bf16 MFMA) + top-32 candidates, chunked over tokens
  for (int c=0;c<NCHUNK;c++){
    gemm_bt<false><<<dim3(MDB/128, CHUNK/128),256,0,stream>>>(
      q_b16 + (size_t)c*CHUNK*DMODEL, dbk16, nullptr, nullptr, scores, nullptr, MDB, DMODEL);
    topk_kernel<<<CHUNK,256,0,stream>>>(scores, cand, c*CHUNK);
  }
  // exact fp32 rescore -> final top-16 indices
  rescore_kernel<<<TOKENS,256,0,stream>>>(q_f32, dbk, cand, idxf);
  // per-token attention over 16 retrieved memories (fp32)
  attn_kernel<<<TOKENS,256,0,stream>>>(q_f32, dbk, dbv, idxf, attn16);

  // c_proj + residual
  gemm_bt<false><<<dim3(DMODEL/128, TOKENS/128),256,0,stream>>>(
    attn16, cp_t, cpb, x, resid2, nullptr, DMODEL, DMODEL);
  // ln2
  ln_kernel<<<TOKENS,256,0,stream>>>(resid2, ln2g, ln2b, nullptr, h2_16);
  // fc + gelu
  gemm_bt<true><<<dim3(DFF/128, TOKENS/128),256,0,stream>>>(
    h2_16, fc_t, fcb, nullptr, nullptr, ff1, DFF, DMODEL);
  // proj + residual2 -> out
  gemm_bt<false><<<dim3(DMODEL/128, TOKENS/128),256,0,stream>>>(
    ff1, pj_t, pjb, resid2, out, nullptr, DMODEL, DFF);
}

// Round 2
// 1318.324 us; speedup vs baseline: 1.7286x; 1.7286x over previous
//
#include <hip/hip_runtime.h>

#define TOKENS 4096
#define DMODEL 768
#define NHEAD 12
#define HDIM 64
#define KSEL 16
#define MDB 32768
#define DFF 3072
#define CHUNK 512
#define NCHUNK 8
#define CAP 128

typedef __attribute__((ext_vector_type(8))) short short8;
typedef __attribute__((ext_vector_type(8))) unsigned short ushort8v;
typedef __attribute__((ext_vector_type(4))) float floatx4;

__device__ __forceinline__ unsigned short f2b(float f){
  unsigned int x = __float_as_uint(f);
  unsigned int r = (x + 0x7FFFu + ((x >> 16) & 1u)) >> 16;
  return (unsigned short)r;
}

__device__ __forceinline__ float gelu_new(float x){
  float x3 = x*x*x;
  float t = tanhf(0.7978845608028654f*(x + 0.044715f*x3));
  return 0.5f*x*(1.0f+t);
}

// bf16 bits -> monotonic 16-bit ordered key
__device__ __forceinline__ unsigned int ordb(unsigned short u){
  return (u & 0x8000u) ? (unsigned int)((~u) & 0xFFFFu) : (unsigned int)(u | 0x8000u);
}

// ---------------- transpose-cast fp32 [R,C](ld) -> bf16 [C,R] ----------------
__global__ __launch_bounds__(256) void tcast_kernel(
    const float* __restrict__ src, unsigned short* __restrict__ dst,
    int R, int C, int ld)
{
  __shared__ float t[32][33];
  int r0 = blockIdx.y*32, c0 = blockIdx.x*32;
  int tx = threadIdx.x & 31, ty = threadIdx.x >> 5;
  #pragma unroll
  for (int i=0;i<4;i++){ int r = ty + i*8; t[r][tx] = src[(size_t)(r0+r)*ld + c0 + tx]; }
  __syncthreads();
  #pragma unroll
  for (int i=0;i<4;i++){ int c = ty + i*8; dst[(size_t)(c0+c)*R + r0 + tx] = f2b(t[tx][c]); }
}

// ---------------- straight cast fp32 -> bf16 ----------------
__global__ __launch_bounds__(256) void cast_bf16_kernel(
    const float* __restrict__ src, unsigned short* __restrict__ dst, int n4)
{
  int i = blockIdx.x*256 + threadIdx.x;
  if (i < n4){
    float4 f = reinterpret_cast<const float4*>(src)[i];
    ushort4 u; u.x = f2b(f.x); u.y = f2b(f.y); u.z = f2b(f.z); u.w = f2b(f.w);
    reinterpret_cast<ushort4*>(dst)[i] = u;
  }
}

// ---------------- layernorm (768), outputs fp32 and/or bf16 ----------------
__global__ __launch_bounds__(256) void ln_kernel(
    const float* __restrict__ x, const float* __restrict__ g, const float* __restrict__ b,
    float* __restrict__ of, unsigned short* __restrict__ ob)
{
  const int token = blockIdx.x, tid = threadIdx.x;
  const float* xr = x + (size_t)token*DMODEL;
  float v[3];
  #pragma unroll
  for (int i=0;i<3;i++) v[i] = xr[tid + i*256];
  float s = v[0]+v[1]+v[2];
  __shared__ float red[8];
  #pragma unroll
  for (int off=32; off; off>>=1) s += __shfl_down(s, off);
  int lane = tid & 63, wv = tid >> 6;
  if (lane == 0) red[wv] = s;
  __syncthreads();
  if (tid == 0) red[4] = (red[0]+red[1]+red[2]+red[3]) * (1.0f/768.0f);
  __syncthreads();
  float mean = red[4];
  float d0 = v[0]-mean, d1 = v[1]-mean, d2 = v[2]-mean;
  float q = d0*d0 + d1*d1 + d2*d2;
  __syncthreads();
  #pragma unroll
  for (int off=32; off; off>>=1) q += __shfl_down(q, off);
  if (lane == 0) red[wv] = q;
  __syncthreads();
  if (tid == 0) red[5] = rsqrtf((red[0]+red[1]+red[2]+red[3]) * (1.0f/768.0f) + 1e-5f);
  __syncthreads();
  float rstd = red[5];
  #pragma unroll
  for (int i=0;i<3;i++){
    int d = tid + i*256;
    float o = (v[i]-mean)*rstd*g[d] + b[d];
    if (of) of[(size_t)token*DMODEL + d] = o;
    if (ob) ob[(size_t)token*DMODEL + d] = f2b(o);
  }
}

// ---------------- fp32 SGEMM for q (precision-critical) ----------------
__global__ __launch_bounds__(256) void sgemm_q(
    const float* __restrict__ A, const float* __restrict__ W,
    const float* __restrict__ bias, float* __restrict__ qf,
    unsigned short* __restrict__ qb)
{
  __shared__ float As[16][65];
  __shared__ float Bs[16][65];
  const int tid = threadIdx.x;
  const int tx = tid & 15, ty = tid >> 4;
  const int m0 = blockIdx.y * 64, n0 = blockIdx.x * 64;
  float acc[4][4] = {};
  for (int k0 = 0; k0 < DMODEL; k0 += 16){
    #pragma unroll
    for (int i=0;i<4;i++){
      int lin = tid + i*256;
      int r = lin >> 4, c = lin & 15;
      As[c][r] = A[(size_t)(m0+r)*DMODEL + k0 + c];
    }
    #pragma unroll
    for (int i=0;i<4;i++){
      int lin = tid + i*256;
      int r = lin >> 6, c = lin & 63;
      Bs[r][c] = W[(size_t)(k0+r)*(3*DMODEL) + n0 + c];
    }
    __syncthreads();
    #pragma unroll
    for (int k=0;k<16;k++){
      float av[4], bv[4];
      #pragma unroll
      for (int i=0;i<4;i++) av[i] = As[k][ty + 16*i];
      #pragma unroll
      for (int j=0;j<4;j++) bv[j] = Bs[k][tx + 16*j];
      #pragma unroll
      for (int i=0;i<4;i++)
        #pragma unroll
        for (int j=0;j<4;j++)
          acc[i][j] += av[i]*bv[j];
    }
    __syncthreads();
  }
  #pragma unroll
  for (int i=0;i<4;i++){
    int m = m0 + ty + 16*i;
    #pragma unroll
    for (int j=0;j<4;j++){
      int n = n0 + tx + 16*j;
      float v2 = acc[i][j] + bias[n];
      qf[(size_t)m*DMODEL + n] = v2;
      qb[(size_t)m*DMODEL + n] = f2b(v2);
    }
  }
}

// ---------------- bf16 MFMA GEMM: C[m,n] = A[m,k] * Bt[n,k]^T ----------------
// 128x128 tile, BK=32, global_load_lds width-16 staging, swizzled LDS layout.
template<bool GELU>
__global__ __launch_bounds__(256) void gemm_bt(
    const unsigned short* __restrict__ A,
    const unsigned short* __restrict__ Bt,
    const float* __restrict__ bias,
    const float* __restrict__ resid,
    float* __restrict__ Cf,
    unsigned short* __restrict__ Cb,
    int N, int K)
{
  __shared__ __align__(16) unsigned short As[128*32];
  __shared__ __align__(16) unsigned short Bs[128*32];
  const int tid = threadIdx.x;
  const int wave = tid >> 6;
  const int lane = tid & 63;
  const int lr = lane & 15;
  const int quad = lane >> 4;
  const int m0 = blockIdx.y * 128;
  const int n0 = blockIdx.x * 128;
  // staging: wave-uniform LDS base + lane*16B. lane l -> row srow=l>>2, stored slot kst=l&3.
  // swizzle: slot kst of row r holds global k-chunk (kst ^ (r&3)).
  const int srow = lane >> 2;
  const int kst  = lane & 3;
  const int ksrc = (kst ^ (srow & 3)) << 3;   // element offset of src k-chunk
  const int sw   = quad ^ (lr & 3);           // slot to read chunk `quad` from

  floatx4 acc[2][8];
  #pragma unroll
  for (int t=0;t<2;t++)
    #pragma unroll
    for (int n=0;n<8;n++)
      acc[t][n] = (floatx4)0.0f;

  for (int k0 = 0; k0 < K; k0 += 32){
    #pragma unroll
    for (int j=0;j<2;j++){
      const int rbase = wave*32 + j*16;
      const unsigned short* ga = A  + (size_t)(m0 + rbase + srow)*K + k0 + ksrc;
      const unsigned short* gb = Bt + (size_t)(n0 + rbase + srow)*K + k0 + ksrc;
      __builtin_amdgcn_global_load_lds(
        (const __attribute__((address_space(1))) void*)ga,
        (__attribute__((address_space(3))) void*)(As + rbase*32), 16, 0, 0);
      __builtin_amdgcn_global_load_lds(
        (const __attribute__((address_space(1))) void*)gb,
        (__attribute__((address_space(3))) void*)(Bs + rbase*32), 16, 0, 0);
    }
    __syncthreads();
    short8 af[2], bq[8];
    #pragma unroll
    for (int t=0;t<2;t++){
      int row = wave*32 + t*16 + lr;
      af[t] = *reinterpret_cast<const short8*>(&As[row*32 + sw*8]);
    }
    #pragma unroll
    for (int n=0;n<8;n++){
      int row = n*16 + lr;
      bq[n] = *reinterpret_cast<const short8*>(&Bs[row*32 + sw*8]);
    }
    #pragma unroll
    for (int t=0;t<2;t++)
      #pragma unroll
      for (int n=0;n<8;n++)
        acc[t][n] = __builtin_amdgcn_mfma_f32_16x16x32_bf16(af[t], bq[n], acc[t][n], 0, 0, 0);
    __syncthreads();
  }

  #pragma unroll
  for (int t=0;t<2;t++){
    #pragma unroll
    for (int n=0;n<8;n++){
      int ng = n0 + n*16 + lr;
      float bi = bias ? bias[ng] : 0.0f;
      #pragma unroll
      for (int r=0;r<4;r++){
        int mg = m0 + wave*32 + t*16 + quad*4 + r;
        float v = acc[t][n][r] + bi;
        if (resid) v += resid[(size_t)mg*N + ng];
        if (GELU) v = gelu_new(v);
        if (Cf) Cf[(size_t)mg*N + ng] = v;
        if (Cb) Cb[(size_t)mg*N + ng] = f2b(v);
      }
    }
  }
}

// ---------------- histogram radix-select: all candidates >= 32nd value ----------------
__global__ __launch_bounds__(256) void topk_kernel(
    const unsigned short* __restrict__ scores, int* __restrict__ cand,
    int* __restrict__ cand_cnt, int token_base)
{
  const int tl = blockIdx.x, tid = threadIdx.x;
  const ushort8v* row8 = reinterpret_cast<const ushort8v*>(scores + (size_t)tl*MDB);
  __shared__ unsigned int hist[8192];
  __shared__ unsigned int ps[256];
  __shared__ int cidx[CAP];
  __shared__ int misc[2];
  #pragma unroll
  for (int i=0;i<32;i++) hist[tid + i*256] = 0;
  __syncthreads();
  for (int it=0; it<16; ++it){
    ushort8v w = row8[tid + (it<<8)];
    #pragma unroll
    for (int j=0;j<8;j++){
      unsigned int b = ordb((unsigned short)w[j]) >> 3;
      atomicAdd(&hist[b], 1u);
    }
  }
  __syncthreads();
  unsigned int s = 0;
  #pragma unroll
  for (int i=0;i<32;i++) s += hist[(tid<<5)+i];
  ps[tid] = s;
  __syncthreads();
  if (tid == 0){
    unsigned int cum = 0; int seg = 0;
    for (int s2=255; s2>=0; --s2){ cum += ps[s2]; if (cum >= 32u){ seg = s2; break; } }
    unsigned int c2 = cum - ps[seg];
    int B = seg << 5;
    for (int b2=(seg<<5)+31; b2>=(seg<<5); --b2){ c2 += hist[b2]; if (c2 >= 32u){ B = b2; break; } }
    misc[0] = B; misc[1] = 0;
  }
  __syncthreads();
  const unsigned int B = (unsigned int)misc[0];
  for (int it=0; it<16; ++it){
    ushort8v w = row8[tid + (it<<8)];
    int e0 = (tid + (it<<8)) << 3;
    #pragma unroll
    for (int j=0;j<8;j++){
      unsigned int b = ordb((unsigned short)w[j]) >> 3;
      if (b >= B){
        int pos = atomicAdd(&misc[1], 1);
        if (pos < CAP) cidx[pos] = e0 + j;
      }
    }
  }
  __syncthreads();
  int cnt = misc[1]; if (cnt > CAP) cnt = CAP;
  if (tid == 0) cand_cnt[token_base + tl] = cnt;
  for (int i=tid; i<cnt; i+=256) cand[(size_t)(token_base+tl)*CAP + i] = cidx[i];
}

// ---------------- exact fp32 rescore of <=CAP candidates -> top-16 ----------------
__global__ __launch_bounds__(256) void rescore_kernel(
    const float* __restrict__ qf, const float* __restrict__ dbk,
    const int* __restrict__ cand, const int* __restrict__ cand_cnt,
    int* __restrict__ idxo)
{
  const int token = blockIdx.x, tid = threadIdx.x;
  __shared__ float qs[768];
  __shared__ int cs[CAP];
  __shared__ float sval[CAP];
  #pragma unroll
  for (int i=0;i<3;i++) qs[tid + i*256] = qf[(size_t)token*DMODEL + tid + i*256];
  if (tid < CAP) cs[tid] = cand[(size_t)token*CAP + tid];
  __syncthreads();
  const int cnt = cand_cnt[token];
  const int c = tid >> 3, sub = tid & 7;
  const float* qp = qs + sub*96;
  for (int pass = 0; pass*32 < cnt; ++pass){
    int ci = pass*32 + c;
    if (ci < cnt){
      const float* kr = dbk + (size_t)cs[ci]*DMODEL + sub*96;
      float s = 0.f;
      #pragma unroll
      for (int j=0;j<24;j++){
        float4 a = reinterpret_cast<const float4*>(qp)[j];
        float4 b4 = reinterpret_cast<const float4*>(kr)[j];
        s += a.x*b4.x + a.y*b4.y + a.z*b4.z + a.w*b4.w;
      }
      s += __shfl_xor(s, 1); s += __shfl_xor(s, 2); s += __shfl_xor(s, 4);
      if (sub == 0) sval[ci] = s;
    }
  }
  __syncthreads();
  if (tid < 64){
    float v0 = (tid < cnt)     ? sval[tid]    : -3.4e38f;
    float v1 = (tid+64 < cnt)  ? sval[tid+64] : -3.4e38f;
    int   i0 = (tid < cnt)     ? cs[tid]      : 0x7FFFFFFF;
    int   i1 = (tid+64 < cnt)  ? cs[tid+64]   : 0x7FFFFFFF;
    for (int r=0;r<KSEL;r++){
      float mv; int mi, ms;
      if (v1 > v0 || (v1 == v0 && i1 < i0)){ mv = v1; mi = i1; ms = 1; }
      else { mv = v0; mi = i0; ms = 0; }
      int ml = tid;
      #pragma unroll
      for (int off=32; off; off>>=1){
        float ov = __shfl_xor(mv, off);
        int oi = __shfl_xor(mi, off);
        int ol = __shfl_xor(ml, off);
        int os = __shfl_xor(ms, off);
        if (ov > mv || (ov == mv && oi < mi)){ mv = ov; mi = oi; ml = ol; ms = os; }
      }
      if (tid == 0) idxo[(size_t)token*KSEL + r] = mi;
      if (tid == ml){
        if (ms){ v1 = -3.4e38f; i1 = 0x7FFFFFFF; }
        else   { v0 = -3.4e38f; i0 = 0x7FFFFFFF; }
      }
    }
  }
}

// ---------------- per-token softmax attention over 16 memories ----------------
__global__ __launch_bounds__(256) void attn_kernel(
    const float* __restrict__ qf, const float* __restrict__ dbk, const float* __restrict__ dbv,
    const int* __restrict__ idx, unsigned short* __restrict__ ao)
{
  const int token = blockIdx.x, tid = threadIdx.x;
  __shared__ float qs[768];
  __shared__ int ixs[16];
  __shared__ float awgt[12][16];
  #pragma unroll
  for (int i=0;i<3;i++) qs[tid + i*256] = qf[(size_t)token*DMODEL + tid + i*256];
  if (tid < 16) ixs[tid] = idx[(size_t)token*KSEL + tid];
  __syncthreads();
  if (tid < 192){
    int m = tid / 12, h = tid - m*12;
    const float4* kr = reinterpret_cast<const float4*>(dbk + (size_t)ixs[m]*DMODEL + h*HDIM);
    const float4* qr = reinterpret_cast<const float4*>(qs + h*HDIM);
    float s = 0.f;
    #pragma unroll
    for (int j=0;j<16;j++){
      float4 a = qr[j], b4 = kr[j];
      s += a.x*b4.x + a.y*b4.y + a.z*b4.z + a.w*b4.w;
    }
    awgt[h][m] = s * 0.125f;
  }
  __syncthreads();
  if (tid < 12){
    float mx = awgt[tid][0];
    #pragma unroll
    for (int m=1;m<16;m++) mx = fmaxf(mx, awgt[tid][m]);
    float ssum = 0.f;
    float e[16];
    #pragma unroll
    for (int m=0;m<16;m++){ e[m] = expf(awgt[tid][m]-mx); ssum += e[m]; }
    float inv = 1.0f/ssum;
    #pragma unroll
    for (int m=0;m<16;m++) awgt[tid][m] = e[m]*inv;
  }
  __syncthreads();
  #pragma unroll
  for (int i=0;i<3;i++){
    int d = tid + i*256;
    int h = d >> 6;
    float s = 0.f;
    #pragma unroll
    for (int m=0;m<16;m++) s += awgt[h][m] * dbv[(size_t)ixs[m]*DMODEL + d];
    ao[(size_t)token*DMODEL + d] = f2b(s);
  }
}

extern "C" void kernel_launch(void* const* d_in, const int* in_sizes, int n_in,
                              void* d_out, int out_size, void* d_ws, size_t ws_size,
                              hipStream_t stream) {
  (void)in_sizes; (void)n_in; (void)out_size; (void)ws_size;
  const float* x    = (const float*)d_in[0];
  const float* dbk  = (const float*)d_in[1];
  const float* dbv  = (const float*)d_in[2];
  const float* ln1g = (const float*)d_in[3];
  const float* ln1b = (const float*)d_in[4];
  const float* attw = (const float*)d_in[5];
  const float* attb = (const float*)d_in[6];
  const float* cpw  = (const float*)d_in[7];
  const float* cpb  = (const float*)d_in[8];
  const float* ln2g = (const float*)d_in[9];
  const float* ln2b = (const float*)d_in[10];
  const float* fcw  = (const float*)d_in[11];
  const float* fcb  = (const float*)d_in[12];
  const float* pjw  = (const float*)d_in[13];
  const float* pjb  = (const float*)d_in[14];
  float* out = (float*)d_out;

  char* p = (char*)d_ws;
  auto alloc = [&](size_t bytes) -> void* {
    void* r = (void*)p; p += (bytes + 255) & ~(size_t)255; return r;
  };
  float* h_f32            = (float*)alloc((size_t)TOKENS*DMODEL*4);
  float* q_f32            = (float*)alloc((size_t)TOKENS*DMODEL*4);
  unsigned short* q_b16   = (unsigned short*)alloc((size_t)TOKENS*DMODEL*2);
  unsigned short* dbk16   = (unsigned short*)alloc((size_t)MDB*DMODEL*2);
  unsigned short* cp_t    = (unsigned short*)alloc((size_t)DMODEL*DMODEL*2);
  unsigned short* fc_t    = (unsigned short*)alloc((size_t)DMODEL*DFF*2);
  unsigned short* pj_t    = (unsigned short*)alloc((size_t)DMODEL*DFF*2);
  unsigned short* scores16= (unsigned short*)alloc((size_t)CHUNK*MDB*2);
  int* cand               = (int*)alloc((size_t)TOKENS*CAP*4);
  int* cand_cnt           = (int*)alloc((size_t)TOKENS*4);
  int* idxf               = (int*)alloc((size_t)TOKENS*KSEL*4);
  unsigned short* attn16  = (unsigned short*)alloc((size_t)TOKENS*DMODEL*2);
  float* resid2           = (float*)alloc((size_t)TOKENS*DMODEL*4);
  unsigned short* h2_16   = (unsigned short*)alloc((size_t)TOKENS*DMODEL*2);
  unsigned short* ff1     = (unsigned short*)alloc((size_t)TOKENS*DFF*2);

  // weight casts / transposes to [N,K] bf16
  tcast_kernel<<<dim3(24,24),256,0,stream>>>(cpw,  cp_t, DMODEL, DMODEL, DMODEL);
  tcast_kernel<<<dim3(96,24),256,0,stream>>>(fcw,  fc_t, DMODEL, DFF,    DFF);
  tcast_kernel<<<dim3(24,96),256,0,stream>>>(pjw,  pj_t, DFF,    DMODEL, DMODEL);
  cast_bf16_kernel<<<(MDB*DMODEL/4+255)/256,256,0,stream>>>(dbk, dbk16, MDB*DMODEL/4);

  // ln1 -> h (fp32 for precision-critical q GEMM)
  ln_kernel<<<TOKENS,256,0,stream>>>(x, ln1g, ln1b, h_f32, nullptr);
  // q = h @ c_attn_w[:, :768] + b  (fp32; k,v slices of c_attn are dead code)
  sgemm_q<<<dim3(12, TOKENS/64),256,0,stream>>>(h_f32, attw, attb, q_f32, q_b16);

  // approximate scores (bf16 MFMA, bf16 output) + candidate select, chunked
  for (int c=0;c<NCHUNK;c++){
    gemm_bt<false><<<dim3(MDB/128, CHUNK/128),256,0,stream>>>(
      q_b16 + (size_t)c*CHUNK*DMODEL, dbk16, nullptr, nullptr, nullptr, scores16, MDB, DMODEL);
    topk_kernel<<<CHUNK,256,0,stream>>>(scores16, cand, cand_cnt, c*CHUNK);
  }
  // exact fp32 rescore -> final top-16 indices
  rescore_kernel<<<TOKENS,256,0,stream>>>(q_f32, dbk, cand, cand_cnt, idxf);
  // per-token attention over 16 retrieved memories (fp32)
  attn_kernel<<<TOKENS,256,0,stream>>>(q_f32, dbk, dbv, idxf, attn16);

  // c_proj + residual
  gemm_bt<false><<<dim3(DMODEL/128, TOKENS/128),256,0,stream>>>(
    attn16, cp_t, cpb, x, resid2, nullptr, DMODEL, DMODEL);
  // ln2
  ln_kernel<<<TOKENS,256,0,stream>>>(resid2, ln2g, ln2b, nullptr, h2_16);
  // fc + gelu
  gemm_bt<true><<<dim3(DFF/128, TOKENS/128),256,0,stream>>>(
    h2_16, fc_t, fcb, nullptr, nullptr, ff1, DFF, DMODEL);
  // proj + residual2 -> out
  gemm_bt<false><<<dim3(DMODEL/128, TOKENS/128),256,0,stream>>>(
    ff1, pj_t, pjb, resid2, out, nullptr, DMODEL, DFF);
}

// Round 5
// 1315.030 us; speedup vs baseline: 1.7329x; 1.0025x over previous
//
#include <hip/hip_runtime.h>

#define TOKENS 4096
#define DMODEL 768
#define NHEAD 12
#define HDIM 64
#define KSEL 16
#define MDB 32768
#define DFF 3072
#define CHUNK 512
#define NCHUNK 8
#define CAP 128

typedef __attribute__((ext_vector_type(8))) short short8;
typedef __attribute__((ext_vector_type(8))) unsigned short ushort8v;
typedef __attribute__((ext_vector_type(4))) float floatx4;

__device__ __forceinline__ unsigned short f2b(float f){
  unsigned int x = __float_as_uint(f);
  unsigned int r = (x + 0x7FFFu + ((x >> 16) & 1u)) >> 16;
  return (unsigned short)r;
}

__device__ __forceinline__ float gelu_new(float x){
  float x3 = x*x*x;
  float t = tanhf(0.7978845608028654f*(x + 0.044715f*x3));
  return 0.5f*x*(1.0f+t);
}

// bf16 bits -> monotonic 16-bit ordered key
__device__ __forceinline__ unsigned int ordb(unsigned short u){
  return (u & 0x8000u) ? (unsigned int)((~u) & 0xFFFFu) : (unsigned int)(u | 0x8000u);
}

// ---------------- transpose-cast fp32 [R,C](ld) -> bf16 [C,R] ----------------
__global__ __launch_bounds__(256) void tcast_kernel(
    const float* __restrict__ src, unsigned short* __restrict__ dst,
    int R, int C, int ld)
{
  __shared__ float t[32][33];
  int r0 = blockIdx.y*32, c0 = blockIdx.x*32;
  int tx = threadIdx.x & 31, ty = threadIdx.x >> 5;
  #pragma unroll
  for (int i=0;i<4;i++){ int r = ty + i*8; t[r][tx] = src[(size_t)(r0+r)*ld + c0 + tx]; }
  __syncthreads();
  #pragma unroll
  for (int i=0;i<4;i++){ int c = ty + i*8; dst[(size_t)(c0+c)*R + r0 + tx] = f2b(t[tx][c]); }
}

// ---------------- straight cast fp32 -> bf16 ----------------
__global__ __launch_bounds__(256) void cast_bf16_kernel(
    const float* __restrict__ src, unsigned short* __restrict__ dst, int n4)
{
  int i = blockIdx.x*256 + threadIdx.x;
  if (i < n4){
    float4 f = reinterpret_cast<const float4*>(src)[i];
    ushort4 u; u.x = f2b(f.x); u.y = f2b(f.y); u.z = f2b(f.z); u.w = f2b(f.w);
    reinterpret_cast<ushort4*>(dst)[i] = u;
  }
}

// ---------------- layernorm (768), outputs fp32 and/or bf16 ----------------
__global__ __launch_bounds__(256) void ln_kernel(
    const float* __restrict__ x, const float* __restrict__ g, const float* __restrict__ b,
    float* __restrict__ of, unsigned short* __restrict__ ob)
{
  const int token = blockIdx.x, tid = threadIdx.x;
  const float* xr = x + (size_t)token*DMODEL;
  float v[3];
  #pragma unroll
  for (int i=0;i<3;i++) v[i] = xr[tid + i*256];
  float s = v[0]+v[1]+v[2];
  __shared__ float red[8];
  #pragma unroll
  for (int off=32; off; off>>=1) s += __shfl_down(s, off);
  int lane = tid & 63, wv = tid >> 6;
  if (lane == 0) red[wv] = s;
  __syncthreads();
  if (tid == 0) red[4] = (red[0]+red[1]+red[2]+red[3]) * (1.0f/768.0f);
  __syncthreads();
  float mean = red[4];
  float d0 = v[0]-mean, d1 = v[1]-mean, d2 = v[2]-mean;
  float q = d0*d0 + d1*d1 + d2*d2;
  __syncthreads();
  #pragma unroll
  for (int off=32; off; off>>=1) q += __shfl_down(q, off);
  if (lane == 0) red[wv] = q;
  __syncthreads();
  if (tid == 0) red[5] = rsqrtf((red[0]+red[1]+red[2]+red[3]) * (1.0f/768.0f) + 1e-5f);
  __syncthreads();
  float rstd = red[5];
  #pragma unroll
  for (int i=0;i<3;i++){
    int d = tid + i*256;
    float o = (v[i]-mean)*rstd*g[d] + b[d];
    if (of) of[(size_t)token*DMODEL + d] = o;
    if (ob) ob[(size_t)token*DMODEL + d] = f2b(o);
  }
}

// ---------------- fp32 SGEMM for q (precision-critical, R2-verbatim) ----------------
__global__ __launch_bounds__(256) void sgemm_q(
    const float* __restrict__ A, const float* __restrict__ W,
    const float* __restrict__ bias, float* __restrict__ qf,
    unsigned short* __restrict__ qb)
{
  __shared__ float As[16][65];
  __shared__ float Bs[16][65];
  const int tid = threadIdx.x;
  const int tx = tid & 15, ty = tid >> 4;
  const int m0 = blockIdx.y * 64, n0 = blockIdx.x * 64;
  float acc[4][4] = {};
  for (int k0 = 0; k0 < DMODEL; k0 += 16){
    #pragma unroll
    for (int i=0;i<4;i++){
      int lin = tid + i*256;
      int r = lin >> 4, c = lin & 15;
      As[c][r] = A[(size_t)(m0+r)*DMODEL + k0 + c];
    }
    #pragma unroll
    for (int i=0;i<4;i++){
      int lin = tid + i*256;
      int r = lin >> 6, c = lin & 63;
      Bs[r][c] = W[(size_t)(k0+r)*(3*DMODEL) + n0 + c];
    }
    __syncthreads();
    #pragma unroll
    for (int k=0;k<16;k++){
      float av[4], bv[4];
      #pragma unroll
      for (int i=0;i<4;i++) av[i] = As[k][ty + 16*i];
      #pragma unroll
      for (int j=0;j<4;j++) bv[j] = Bs[k][tx + 16*j];
      #pragma unroll
      for (int i=0;i<4;i++)
        #pragma unroll
        for (int j=0;j<4;j++)
          acc[i][j] += av[i]*bv[j];
    }
    __syncthreads();
  }
  #pragma unroll
  for (int i=0;i<4;i++){
    int m = m0 + ty + 16*i;
    #pragma unroll
    for (int j=0;j<4;j++){
      int n = n0 + tx + 16*j;
      float v2 = acc[i][j] + bias[n];
      qf[(size_t)m*DMODEL + n] = v2;
      qb[(size_t)m*DMODEL + n] = f2b(v2);
    }
  }
}

// ---------------- bf16 MFMA GEMM: C[m,n] = A[m,k] * Bt[n,k]^T ----------------
// 128x128 tile, BK=32, global_load_lds width-16 staging, swizzled LDS layout.
template<bool GELU>
__global__ __launch_bounds__(256) void gemm_bt(
    const unsigned short* __restrict__ A,
    const unsigned short* __restrict__ Bt,
    const float* __restrict__ bias,
    const float* __restrict__ resid,
    float* __restrict__ Cf,
    unsigned short* __restrict__ Cb,
    int N, int K)
{
  __shared__ __align__(16) unsigned short As[128*32];
  __shared__ __align__(16) unsigned short Bs[128*32];
  const int tid = threadIdx.x;
  const int wave = tid >> 6;
  const int lane = tid & 63;
  const int lr = lane & 15;
  const int quad = lane >> 4;
  const int m0 = blockIdx.y * 128;
  const int n0 = blockIdx.x * 128;
  const int srow = lane >> 2;
  const int kst  = lane & 3;
  const int ksrc = (kst ^ (srow & 3)) << 3;
  const int sw   = quad ^ (lr & 3);

  floatx4 acc[2][8];
  #pragma unroll
  for (int t=0;t<2;t++)
    #pragma unroll
    for (int n=0;n<8;n++)
      acc[t][n] = (floatx4)0.0f;

  for (int k0 = 0; k0 < K; k0 += 32){
    #pragma unroll
    for (int j=0;j<2;j++){
      const int rbase = wave*32 + j*16;
      const unsigned short* ga = A  + (size_t)(m0 + rbase + srow)*K + k0 + ksrc;
      const unsigned short* gb = Bt + (size_t)(n0 + rbase + srow)*K + k0 + ksrc;
      __builtin_amdgcn_global_load_lds(
        (const __attribute__((address_space(1))) void*)ga,
        (__attribute__((address_space(3))) void*)(As + rbase*32), 16, 0, 0);
      __builtin_amdgcn_global_load_lds(
        (const __attribute__((address_space(1))) void*)gb,
        (__attribute__((address_space(3))) void*)(Bs + rbase*32), 16, 0, 0);
    }
    __syncthreads();
    short8 af[2], bq[8];
    #pragma unroll
    for (int t=0;t<2;t++){
      int row = wave*32 + t*16 + lr;
      af[t] = *reinterpret_cast<const short8*>(&As[row*32 + sw*8]);
    }
    #pragma unroll
    for (int n=0;n<8;n++){
      int row = n*16 + lr;
      bq[n] = *reinterpret_cast<const short8*>(&Bs[row*32 + sw*8]);
    }
    #pragma unroll
    for (int t=0;t<2;t++)
      #pragma unroll
      for (int n=0;n<8;n++)
        acc[t][n] = __builtin_amdgcn_mfma_f32_16x16x32_bf16(af[t], bq[n], acc[t][n], 0, 0, 0);
    __syncthreads();
  }

  #pragma unroll
  for (int t=0;t<2;t++){
    #pragma unroll
    for (int n=0;n<8;n++){
      int ng = n0 + n*16 + lr;
      float bi = bias ? bias[ng] : 0.0f;
      #pragma unroll
      for (int r=0;r<4;r++){
        int mg = m0 + wave*32 + t*16 + quad*4 + r;
        float v = acc[t][n][r] + bi;
        if (resid) v += resid[(size_t)mg*N + ng];
        if (GELU) v = gelu_new(v);
        if (Cf) Cf[(size_t)mg*N + ng] = v;
        if (Cb) Cb[(size_t)mg*N + ng] = f2b(v);
      }
    }
  }
}

// ------- histogram radix-select (R2-proven): all candidates >= bin of 32nd value -------
__global__ __launch_bounds__(256) void topk_kernel(
    const unsigned short* __restrict__ scores, int* __restrict__ cand,
    int* __restrict__ cand_cnt, int token_base)
{
  const int tl = blockIdx.x, tid = threadIdx.x;
  const ushort8v* row8 = reinterpret_cast<const ushort8v*>(scores + (size_t)tl*MDB);
  __shared__ unsigned int hist[8192];
  __shared__ unsigned int ps[256];
  __shared__ int cidx[CAP];
  __shared__ int misc[2];
  #pragma unroll
  for (int i=0;i<32;i++) hist[tid + i*256] = 0;
  __syncthreads();
  for (int it=0; it<16; ++it){
    ushort8v w = row8[tid + (it<<8)];
    #pragma unroll
    for (int j=0;j<8;j++){
      unsigned int b = ordb((unsigned short)w[j]) >> 3;
      atomicAdd(&hist[b], 1u);
    }
  }
  __syncthreads();
  unsigned int s = 0;
  #pragma unroll
  for (int i=0;i<32;i++) s += hist[(tid<<5)+i];
  ps[tid] = s;
  __syncthreads();
  if (tid == 0){
    unsigned int cum = 0; int seg = 0;
    for (int s2=255; s2>=0; --s2){ cum += ps[s2]; if (cum >= 32u){ seg = s2; break; } }
    unsigned int c2 = cum - ps[seg];
    int B = seg << 5;
    for (int b2=(seg<<5)+31; b2>=(seg<<5); --b2){ c2 += hist[b2]; if (c2 >= 32u){ B = b2; break; } }
    misc[0] = B; misc[1] = 0;
  }
  __syncthreads();
  const unsigned int B = (unsigned int)misc[0];
  for (int it=0; it<16; ++it){
    ushort8v w = row8[tid + (it<<8)];
    int e0 = (tid + (it<<8)) << 3;
    #pragma unroll
    for (int j=0;j<8;j++){
      unsigned int b = ordb((unsigned short)w[j]) >> 3;
      if (b >= B){
        int pos = atomicAdd(&misc[1], 1);
        if (pos < CAP) cidx[pos] = e0 + j;
      }
    }
  }
  __syncthreads();
  int cnt = misc[1]; if (cnt > CAP) cnt = CAP;
  if (tid == 0) cand_cnt[token_base + tl] = cnt;
  for (int i=tid; i<cnt; i+=256) cand[(size_t)(token_base+tl)*CAP + i] = cidx[i];
}

// ------- fused: R2 rescore (verbatim arithmetic) -> top-16 -> R2 attn (verbatim) -------
__global__ __launch_bounds__(256) void rescore_attn_kernel(
    const float* __restrict__ qf, const float* __restrict__ dbk, const float* __restrict__ dbv,
    const int* __restrict__ cand, const int* __restrict__ cand_cnt,
    unsigned short* __restrict__ ao)
{
  const int token = blockIdx.x, tid = threadIdx.x;
  __shared__ float qs[768];
  __shared__ int cs[CAP];
  __shared__ float sval[CAP];
  __shared__ int ixs[KSEL];
  __shared__ float awgt[12][KSEL];
  #pragma unroll
  for (int i=0;i<3;i++) qs[tid + i*256] = qf[(size_t)token*DMODEL + tid + i*256];
  if (tid < CAP) cs[tid] = cand[(size_t)token*CAP + tid];
  __syncthreads();
  const int cnt = cand_cnt[token];
  // --- full scores: R2 rescore arithmetic (8 sub-dots of 96, shfl butterfly) ---
  const int c = tid >> 3, sub = tid & 7;
  const float* qp = qs + sub*96;
  for (int pass = 0; pass*32 < cnt; ++pass){
    int ci = pass*32 + c;
    if (ci < cnt){
      const float* kr = dbk + (size_t)cs[ci]*DMODEL + sub*96;
      float s = 0.f;
      #pragma unroll
      for (int j=0;j<24;j++){
        float4 a = reinterpret_cast<const float4*>(qp)[j];
        float4 b4 = reinterpret_cast<const float4*>(kr)[j];
        s += a.x*b4.x + a.y*b4.y + a.z*b4.z + a.w*b4.w;
      }
      s += __shfl_xor(s, 1); s += __shfl_xor(s, 2); s += __shfl_xor(s, 4);
      if (sub == 0) sval[ci] = s;
    }
  }
  __syncthreads();
  // --- top-16 select: R2 two-slot wave select ---
  if (tid < 64){
    float v0 = (tid < cnt)    ? sval[tid]    : -3.4e38f;
    float v1 = (tid+64 < cnt) ? sval[tid+64] : -3.4e38f;
    int   i0 = (tid < cnt)    ? cs[tid]      : 0x7FFFFFFF;
    int   i1 = (tid+64 < cnt) ? cs[tid+64]   : 0x7FFFFFFF;
    for (int r=0;r<KSEL;r++){
      float mv; int mi, ms;
      if (v1 > v0 || (v1 == v0 && i1 < i0)){ mv = v1; mi = i1; ms = 1; }
      else { mv = v0; mi = i0; ms = 0; }
      int ml = tid;
      #pragma unroll
      for (int off=32; off; off>>=1){
        float ov = __shfl_xor(mv, off);
        int oi = __shfl_xor(mi, off);
        int ol = __shfl_xor(ml, off);
        int os = __shfl_xor(ms, off);
        if (ov > mv || (ov == mv && oi < mi)){ mv = ov; mi = oi; ml = ol; ms = os; }
      }
      if (tid == 0) ixs[r] = mi;
      if (tid == ml){
        if (ms){ v1 = -3.4e38f; i1 = 0x7FFFFFFF; }
        else   { v0 = -3.4e38f; i0 = 0x7FFFFFFF; }
      }
    }
  }
  __syncthreads();
  // --- winner head dots: R2 attn arithmetic (16 float4 per head) ---
  if (tid < 192){
    int m = tid / 12, h = tid - m*12;
    const float4* kr = reinterpret_cast<const float4*>(dbk + (size_t)ixs[m]*DMODEL + h*HDIM);
    const float4* qr = reinterpret_cast<const float4*>(qs + h*HDIM);
    float s = 0.f;
    #pragma unroll
    for (int j=0;j<16;j++){
      float4 a = qr[j], b4 = kr[j];
      s += a.x*b4.x + a.y*b4.y + a.z*b4.z + a.w*b4.w;
    }
    awgt[h][m] = s * 0.125f;
  }
  __syncthreads();
  if (tid < 12){
    float mx = awgt[tid][0];
    #pragma unroll
    for (int m=1;m<16;m++) mx = fmaxf(mx, awgt[tid][m]);
    float ssum = 0.f;
    float e[16];
    #pragma unroll
    for (int m=0;m<16;m++){ e[m] = expf(awgt[tid][m]-mx); ssum += e[m]; }
    float inv = 1.0f/ssum;
    #pragma unroll
    for (int m=0;m<16;m++) awgt[tid][m] = e[m]*inv;
  }
  __syncthreads();
  #pragma unroll
  for (int i=0;i<3;i++){
    int d = tid + i*256;
    int h = d >> 6;
    float s = 0.f;
    #pragma unroll
    for (int m=0;m<16;m++) s += awgt[h][m] * dbv[(size_t)ixs[m]*DMODEL + d];
    ao[(size_t)token*DMODEL + d] = f2b(s);
  }
}

extern "C" void kernel_launch(void* const* d_in, const int* in_sizes, int n_in,
                              void* d_out, int out_size, void* d_ws, size_t ws_size,
                              hipStream_t stream) {
  (void)in_sizes; (void)n_in; (void)out_size; (void)ws_size;
  const float* x    = (const float*)d_in[0];
  const float* dbk  = (const float*)d_in[1];
  const float* dbv  = (const float*)d_in[2];
  const float* ln1g = (const float*)d_in[3];
  const float* ln1b = (const float*)d_in[4];
  const float* attw = (const float*)d_in[5];
  const float* attb = (const float*)d_in[6];
  const float* cpw  = (const float*)d_in[7];
  const float* cpb  = (const float*)d_in[8];
  const float* ln2g = (const float*)d_in[9];
  const float* ln2b = (const float*)d_in[10];
  const float* fcw  = (const float*)d_in[11];
  const float* fcb  = (const float*)d_in[12];
  const float* pjw  = (const float*)d_in[13];
  const float* pjb  = (const float*)d_in[14];
  float* out = (float*)d_out;

  char* p = (char*)d_ws;
  auto alloc = [&](size_t bytes) -> void* {
    void* r = (void*)p; p += (bytes + 255) & ~(size_t)255; return r;
  };
  float* h_f32            = (float*)alloc((size_t)TOKENS*DMODEL*4);
  float* q_f32            = (float*)alloc((size_t)TOKENS*DMODEL*4);
  unsigned short* q_b16   = (unsigned short*)alloc((size_t)TOKENS*DMODEL*2);
  unsigned short* dbk16   = (unsigned short*)alloc((size_t)MDB*DMODEL*2);
  unsigned short* cp_t    = (unsigned short*)alloc((size_t)DMODEL*DMODEL*2);
  unsigned short* fc_t    = (unsigned short*)alloc((size_t)DMODEL*DFF*2);
  unsigned short* pj_t    = (unsigned short*)alloc((size_t)DMODEL*DFF*2);
  unsigned short* scores16= (unsigned short*)alloc((size_t)CHUNK*MDB*2);
  int* cand               = (int*)alloc((size_t)TOKENS*CAP*4);
  int* cand_cnt           = (int*)alloc((size_t)TOKENS*4);
  unsigned short* attn16  = (unsigned short*)alloc((size_t)TOKENS*DMODEL*2);
  float* resid2           = (float*)alloc((size_t)TOKENS*DMODEL*4);
  unsigned short* h2_16   = (unsigned short*)alloc((size_t)TOKENS*DMODEL*2);
  unsigned short* ff1     = (unsigned short*)alloc((size_t)TOKENS*DFF*2);

  // weight casts / transposes to [N,K] bf16
  tcast_kernel<<<dim3(24,24),256,0,stream>>>(cpw,  cp_t, DMODEL, DMODEL, DMODEL);
  tcast_kernel<<<dim3(96,24),256,0,stream>>>(fcw,  fc_t, DMODEL, DFF,    DFF);
  tcast_kernel<<<dim3(24,96),256,0,stream>>>(pjw,  pj_t, DFF,    DMODEL, DMODEL);
  cast_bf16_kernel<<<(MDB*DMODEL/4+255)/256,256,0,stream>>>(dbk, dbk16, MDB*DMODEL/4);

  // ln1 -> h (fp32 for precision-critical q GEMM)
  ln_kernel<<<TOKENS,256,0,stream>>>(x, ln1g, ln1b, h_f32, nullptr);
  // q = h @ c_attn_w[:, :768] + b  (fp32 R2-verbatim; k,v slices are dead code)
  sgemm_q<<<dim3(12, TOKENS/64),256,0,stream>>>(h_f32, attw, attb, q_f32, q_b16);

  // approximate scores (bf16 MFMA, bf16 output) + candidate select, chunked
  for (int c=0;c<NCHUNK;c++){
    gemm_bt<false><<<dim3(MDB/128, CHUNK/128),256,0,stream>>>(
      q_b16 + (size_t)c*CHUNK*DMODEL, dbk16, nullptr, nullptr, nullptr, scores16, MDB, DMODEL);
    topk_kernel<<<CHUNK,256,0,stream>>>(scores16, cand, cand_cnt, c*CHUNK);
  }
  // fused: exact fp32 rescore (R2 bits) -> top-16 -> softmax -> PV
  rescore_attn_kernel<<<TOKENS,256,0,stream>>>(q_f32, dbk, dbv, cand, cand_cnt, attn16);

  // c_proj + residual
  gemm_bt<false><<<dim3(DMODEL/128, TOKENS/128),256,0,stream>>>(
    attn16, cp_t, cpb, x, resid2, nullptr, DMODEL, DMODEL);
  // ln2
  ln_kernel<<<TOKENS,256,0,stream>>>(resid2, ln2g, ln2b, nullptr, h2_16);
  // fc + gelu
  gemm_bt<true><<<dim3(DFF/128, TOKENS/128),256,0,stream>>>(
    h2_16, fc_t, fcb, nullptr, nullptr, ff1, DFF, DMODEL);
  // proj + residual2 -> out
  gemm_bt<false><<<dim3(DMODEL/128, TOKENS/128),256,0,stream>>>(
    ff1, pj_t, pjb, resid2, out, nullptr, DMODEL, DFF);
}